// Round 9
// baseline (437.914 us; speedup 1.0000x reference)
//
#include <hip/hip_runtime.h>
#include <hip/hip_bf16.h>
#include <math.h>

typedef __attribute__((ext_vector_type(8))) short short8;
typedef __attribute__((ext_vector_type(4))) short short4v;
typedef __attribute__((ext_vector_type(4))) float f32x4;
typedef unsigned short ushort_t;

__device__ __forceinline__ ushort_t f2bf(float f) {
    union { float f; unsigned u; } v; v.f = f;
    unsigned r = v.u + 0x7FFF + ((v.u >> 16) & 1);
    return (ushort_t)(r >> 16);
}
__device__ __forceinline__ float bf2f(short s) {
    union { unsigned u; float f; } v; v.u = ((unsigned)(ushort_t)s) << 16;
    return v.f;
}

// ---- fused convert: x|wq|wk|wv|wo -> bf16, plus packed float2 (cos,sin) table ----
__global__ void cvt_all(const float* __restrict__ x,
                        const float* __restrict__ w0, const float* __restrict__ w1,
                        const float* __restrict__ w2, const float* __restrict__ w3,
                        const float* __restrict__ fc, const float* __restrict__ fs,
                        ushort_t* __restrict__ dst, float2* __restrict__ fcs,
                        int md8, int dd8, int npair4) {
    int i = blockIdx.x * blockDim.x + threadIdx.x;
    int stride = gridDim.x * blockDim.x;
    const int total0 = md8 + 4 * dd8;
    const int total = total0 + npair4;
    for (; i < total; i += stride) {
        if (i < total0) {
            const float* src;
            long off;
            if (i < md8) { src = x; off = i; }
            else {
                int j = i - md8;
                int which = j / dd8;
                off = j - (long)which * dd8;
                src = (which == 0) ? w0 : (which == 1) ? w1 : (which == 2) ? w2 : w3;
            }
            const float4* s = reinterpret_cast<const float4*>(src) + off * 2;
            float4 a = s[0], b = s[1];
            short8 o;
            o[0] = (short)f2bf(a.x); o[1] = (short)f2bf(a.y);
            o[2] = (short)f2bf(a.z); o[3] = (short)f2bf(a.w);
            o[4] = (short)f2bf(b.x); o[5] = (short)f2bf(b.y);
            o[6] = (short)f2bf(b.z); o[7] = (short)f2bf(b.w);
            reinterpret_cast<short8*>(dst)[i] = o;
        } else {
            int j = i - total0;      // 4 (c,s) pairs per iter
            float4 c4 = reinterpret_cast<const float4*>(fc)[j];
            float4 s4 = reinterpret_cast<const float4*>(fs)[j];
            float2* o = fcs + (long)j * 4;
            o[0] = make_float2(c4.x, s4.x);
            o[1] = make_float2(c4.y, s4.y);
            o[2] = make_float2(c4.z, s4.z);
            o[3] = make_float2(c4.w, s4.w);
        }
    }
}

// ============ 256x256 8-phase GEMM (QKV) + fused RoPE(float2 table) + transposed-V ============
__global__ __launch_bounds__(512, 2) void gemm256_qkv(const ushort_t* __restrict__ A,
                                                      const ushort_t* __restrict__ Bw,
                                                      ushort_t* __restrict__ Cout,
                                                      ushort_t* __restrict__ Vt,
                                                      const float2* __restrict__ fcs,
                                                      int M, int N, int K) {
    extern __shared__ __align__(16) ushort_t lds[];
    ushort_t* As = lds;              // 32768 elems
    ushort_t* Bs = lds + 32768;
    const int t = threadIdx.x;
    const int wid = t >> 6, lane = t & 63;
    const int wr = wid >> 2, wc = wid & 3;
    const int lr = lane & 15, lg = lane >> 4;

    const int ntc = N >> 8;
    const int nwg = (M >> 8) * ntc;
    const int bid = blockIdx.y * gridDim.x + blockIdx.x;
    const int cpx = nwg >> 3;
    const int swz = (bid & 7) * cpx + (bid >> 3);
    const int m0 = (swz / ntc) * 256, n0 = (swz % ntc) * 256;

    f32x4 acc[8][4] = {};

    const int r0 = t >> 3;
    const int c0 = (t & 7) ^ (r0 & 7);
    const ushort_t* gA = A + (long)(m0 + r0) * K + c0 * 8;
    const ushort_t* gB = Bw + (long)(n0 + r0) * K + c0 * 8;

    int aoffE[2];
    aoffE[0] = lr * 64 + (((0 + lg) ^ (lr & 7)) << 3);
    aoffE[1] = lr * 64 + (((4 + lg) ^ (lr & 7)) << 3);

    const int nt = K >> 6;   // 32 (even)

#define STAGE_A(X, h) do { const int p_ = (X) & 1;                                             \
    __builtin_amdgcn_global_load_lds((const __attribute__((address_space(1))) unsigned int*)   \
        (gA + (long)((h) * 128) * K + (X) * 64),                                               \
        (__attribute__((address_space(3))) unsigned int*)(As + (p_ * 2 + (h)) * 8192 + t * 8), \
        16, 0, 0);                                                                             \
    __builtin_amdgcn_global_load_lds((const __attribute__((address_space(1))) unsigned int*)   \
        (gA + (long)((h) * 128 + 64) * K + (X) * 64),                                          \
        (__attribute__((address_space(3))) unsigned int*)(As + (p_ * 2 + (h)) * 8192 + 4096 + t * 8), \
        16, 0, 0); } while (0)

#define STAGE_B(X, h) do { const int p_ = (X) & 1;                                             \
    __builtin_amdgcn_global_load_lds((const __attribute__((address_space(1))) unsigned int*)   \
        (gB + (long)((h) * 128) * K + (X) * 64),                                               \
        (__attribute__((address_space(3))) unsigned int*)(Bs + (p_ * 2 + (h)) * 8192 + t * 8), \
        16, 0, 0);                                                                             \
    __builtin_amdgcn_global_load_lds((const __attribute__((address_space(1))) unsigned int*)   \
        (gB + (long)((h) * 128 + 64) * K + (X) * 64),                                          \
        (__attribute__((address_space(3))) unsigned int*)(Bs + (p_ * 2 + (h)) * 8192 + 4096 + t * 8), \
        16, 0, 0); } while (0)

#define MIDSYNC() do {                                             \
    asm volatile("" ::: "memory");                                 \
    __builtin_amdgcn_s_barrier();                                  \
    asm volatile("s_waitcnt lgkmcnt(0)" ::: "memory");             \
    __builtin_amdgcn_sched_barrier(0); } while (0)

#define ENDBAR() do {                                              \
    asm volatile("" ::: "memory");                                 \
    __builtin_amdgcn_s_barrier(); } while (0)

#define MFMA_Q(AROW, BCOL, AR, BR) do {                            \
    __builtin_amdgcn_s_setprio(1);                                 \
    _Pragma("unroll")                                              \
    for (int ks = 0; ks < 2; ++ks)                                 \
        _Pragma("unroll")                                          \
        for (int m = 0; m < 4; ++m)                                \
            _Pragma("unroll")                                      \
            for (int n = 0; n < 2; ++n)                            \
                acc[(AROW) + m][(BCOL) + n] =                      \
                    __builtin_amdgcn_mfma_f32_16x16x32_bf16((AR)[m][ks], (BR)[n][ks], acc[(AROW) + m][(BCOL) + n], 0, 0, 0); \
    __builtin_amdgcn_s_setprio(0); } while (0)

#define KTILE(U, BUF) do {                                                                     \
    const int Asb = ((BUF) * 2 + wr) * 8192;                                                   \
    const int Bcb = ((BUF) * 2 + (wc >> 1)) * 8192 + (wc & 1) * 4096;                          \
    _Pragma("unroll")                                                                          \
    for (int m = 0; m < 4; ++m)                                                                \
        _Pragma("unroll")                                                                      \
        for (int ks = 0; ks < 2; ++ks)                                                         \
            ar[m][ks] = *reinterpret_cast<const short8*>(&As[Asb + m * 1024 + aoffE[ks]]);     \
    _Pragma("unroll")                                                                          \
    for (int n = 0; n < 2; ++n)                                                                \
        _Pragma("unroll")                                                                      \
        for (int ks = 0; ks < 2; ++ks)                                                         \
            br0[n][ks] = *reinterpret_cast<const short8*>(&Bs[Bcb + n * 1024 + aoffE[ks]]);    \
    if ((U) + 1 < nt) STAGE_A((U) + 1, 1);                                                     \
    MIDSYNC();                                                                                 \
    MFMA_Q(0, 0, ar, br0);                                                                     \
    ENDBAR();                                                                                  \
    _Pragma("unroll")                                                                          \
    for (int n = 0; n < 2; ++n)                                                                \
        _Pragma("unroll")                                                                      \
        for (int ks = 0; ks < 2; ++ks)                                                         \
            br1[n][ks] = *reinterpret_cast<const short8*>(&Bs[Bcb + 2048 + n * 1024 + aoffE[ks]]); \
    MIDSYNC();                                                                                 \
    MFMA_Q(0, 2, ar, br1);                                                                     \
    ENDBAR();                                                                                  \
    _Pragma("unroll")                                                                          \
    for (int m = 0; m < 4; ++m)                                                                \
        _Pragma("unroll")                                                                      \
        for (int ks = 0; ks < 2; ++ks)                                                         \
            ar[m][ks] = *reinterpret_cast<const short8*>(&As[Asb + 4096 + m * 1024 + aoffE[ks]]); \
    if ((U) + 2 < nt) STAGE_B((U) + 2, 0);                                                     \
    MIDSYNC();                                                                                 \
    MFMA_Q(4, 2, ar, br1);                                                                     \
    ENDBAR();                                                                                  \
    if ((U) + 2 < nt) { STAGE_A((U) + 2, 0); STAGE_B((U) + 2, 1); }                            \
    asm volatile("" ::: "memory");                                                             \
    __builtin_amdgcn_s_barrier();                                                              \
    MFMA_Q(4, 0, ar, br0);                                                                     \
    if ((U) < nt - 2) {                                                                        \
        asm volatile("s_waitcnt vmcnt(6)" ::: "memory");                                       \
    } else if ((U) == nt - 2) {                                                                \
        asm volatile("s_waitcnt vmcnt(0)" ::: "memory");                                       \
    }                                                                                          \
    __builtin_amdgcn_s_barrier(); } while (0)

    STAGE_A(0, 0); STAGE_A(0, 1); STAGE_B(0, 0); STAGE_B(0, 1);
    STAGE_A(1, 0); STAGE_B(1, 0); STAGE_B(1, 1);
    asm volatile("s_waitcnt vmcnt(6)" ::: "memory");
    __builtin_amdgcn_s_barrier();

    short8 ar[4][2], br0[2][2], br1[2][2];

    for (int U = 0; U < nt; U += 2) {
        KTILE(U, 0);
        KTILE(U + 1, 1);
    }
#undef KTILE
#undef MFMA_Q
#undef ENDBAR
#undef MIDSYNC
#undef STAGE_A
#undef STAGE_B

    // ---- fused epilogue ----
    const int S = 2048;
    #pragma unroll
    for (int m = 0; m < 8; ++m) {
        #pragma unroll
        for (int n = 0; n < 4; ++n) {
            const int col = n0 + wc * 64 + n * 16 + lr;
            const int which = col >> 11;
            const int h = (col >> 7) & 15;
            const int d = col & 127;
            const int rowb = m0 + wr * 128 + m * 16 + lg * 4;
            const int bb = rowb >> 11;
            const int sb = rowb & 2047;
            if (which == 2) {
                short4v o;
                #pragma unroll
                for (int r = 0; r < 4; ++r) o[r] = (short)f2bf(acc[m][n][r]);
                *reinterpret_cast<short4v*>(Vt + ((long)(bb * 16 + h) * 128 + d) * S + sb) = o;
            } else {
                const int i0 = d >> 1;
                #pragma unroll
                for (int r = 0; r < 4; ++r) {
                    const int s = sb + r;
                    float v = acc[m][n][r];
                    float p = __shfl_xor(v, 1);
                    float2 cs = fcs[(long)s * 64 + i0];
                    float o = (lr & 1) ? (p * cs.y + v * cs.x) : (v * cs.x - p * cs.y);
                    Cout[(long)which * M * 2048 + (((long)(bb * 16 + h)) * 2048 + s) * 128 + d] = f2bf(o);
                }
            }
        }
    }
}

// ---------------- GEMM NT 128x128 (proven 2-phase dbuf) — used for wo ----------------
__global__ __launch_bounds__(256) void gemm_nt_f32(const ushort_t* __restrict__ A,
                                                   const ushort_t* __restrict__ Bw,
                                                   float* __restrict__ Cout,
                                                   int M, int N, int K) {
    __shared__ __align__(16) ushort_t As[2 * 128 * 32];
    __shared__ __align__(16) ushort_t Bs[2 * 128 * 32];
    const int t = threadIdx.x;
    const int wid = t >> 6, lane = t & 63;
    const int wm = wid >> 1, wn = wid & 1;
    const int lr = lane & 15, lg = lane >> 4;

    const int ntc = N >> 7;
    const int nwg = (M >> 7) * ntc;
    const int bid = blockIdx.y * gridDim.x + blockIdx.x;
    const int cpx = nwg >> 3;
    const int swz = (bid & 7) * cpx + (bid >> 3);
    const int m0 = (swz / ntc) * 128, n0 = (swz % ntc) * 128;

    f32x4 acc[4][4] = {};

    const int sh0 = wid * 1024 + lane * 8;
    const int sh1 = sh0 + 512;
    const int r0 = sh0 >> 5, c0 = sh0 & 31;
    const int r1 = sh1 >> 5, c1 = sh1 & 31;

    const ushort_t* gA0 = A + (long)(m0 + r0) * K + c0;
    const ushort_t* gA1 = A + (long)(m0 + r1) * K + c1;
    const ushort_t* gB0 = Bw + (long)(n0 + r0) * K + c0;
    const ushort_t* gB1 = Bw + (long)(n0 + r1) * K + c1;

    auto stage = [&](int k0, int nb) {
        ushort_t* as = As + nb * 4096;
        ushort_t* bs = Bs + nb * 4096;
        __builtin_amdgcn_global_load_lds((const __attribute__((address_space(1))) unsigned int*)(gA0 + k0),
                                         (__attribute__((address_space(3))) unsigned int*)(as + sh0), 16, 0, 0);
        __builtin_amdgcn_global_load_lds((const __attribute__((address_space(1))) unsigned int*)(gA1 + k0),
                                         (__attribute__((address_space(3))) unsigned int*)(as + sh1), 16, 0, 0);
        __builtin_amdgcn_global_load_lds((const __attribute__((address_space(1))) unsigned int*)(gB0 + k0),
                                         (__attribute__((address_space(3))) unsigned int*)(bs + sh0), 16, 0, 0);
        __builtin_amdgcn_global_load_lds((const __attribute__((address_space(1))) unsigned int*)(gB1 + k0),
                                         (__attribute__((address_space(3))) unsigned int*)(bs + sh1), 16, 0, 0);
    };

    const int nt = K >> 5;
    stage(0, 0);
    __syncthreads();
    int cur = 0;

    for (int ti = 0; ti < nt; ++ti) {
        if (ti + 1 < nt) stage((ti + 1) << 5, cur ^ 1);
        const ushort_t* as = As + cur * 4096;
        const ushort_t* bs = Bs + cur * 4096;
        short8 af[4], bfr[4];
        #pragma unroll
        for (int m = 0; m < 4; ++m)
            af[m] = *reinterpret_cast<const short8*>(&as[(wm * 64 + m * 16 + lr) * 32 + lg * 8]);
        #pragma unroll
        for (int n = 0; n < 4; ++n)
            bfr[n] = *reinterpret_cast<const short8*>(&bs[(wn * 64 + n * 16 + lr) * 32 + lg * 8]);
        #pragma unroll
        for (int m = 0; m < 4; ++m)
            #pragma unroll
            for (int n = 0; n < 4; ++n)
                acc[m][n] = __builtin_amdgcn_mfma_f32_16x16x32_bf16(af[m], bfr[n], acc[m][n], 0, 0, 0);
        __syncthreads();
        cur ^= 1;
    }

    #pragma unroll
    for (int m = 0; m < 4; ++m) {
        #pragma unroll
        for (int n = 0; n < 4; ++n) {
            const int col = n0 + wn * 64 + n * 16 + lr;
            #pragma unroll
            for (int r = 0; r < 4; ++r) {
                const int row = m0 + wm * 64 + m * 16 + lg * 4 + r;
                Cout[(long)row * N + col] = acc[m][n][r];
            }
        }
    }
}

// ---------------- causal flash attention (folded, T14 + T2 swizzle + T13 defer-max) ----------------
__global__ __launch_bounds__(256, 3) void attn_kernel(const ushort_t* __restrict__ Qp,
                                                      const ushort_t* __restrict__ Kp,
                                                      const ushort_t* __restrict__ Vtg,
                                                      ushort_t* __restrict__ O,
                                                      int S, int H) {
    __shared__ __align__(16) ushort_t Ks[64 * 128];   // linear, XOR-swizzled 16B slots
    __shared__ __align__(16) ushort_t Vs[128 * 64];   // linear, XOR-swizzled 16B slots
    __shared__ __align__(16) ushort_t Pl[4][16][72];
    const int t = threadIdx.x, wid = t >> 6, lane = t & 63;
    const int lr = lane & 15, lg = lane >> 4;
    const int bh = blockIdx.y;
    const int b = bh / H, h = bh % H;
    const ushort_t* Qh = Qp + (long)bh * S * 128;
    const ushort_t* Kh = Kp + (long)bh * S * 128;
    const ushort_t* Vth = Vtg + (long)bh * 128 * S;
    const int nq = S / 64;
    const float scale = 0.08838834764831845f;

    const int ksr = t >> 2;          // K stage row 0..63
    const int vsr = t & 127;         // V stage row (d)
    const int vsc = (t >> 7) * 32;   // V stage col base

    for (int qsel = 0; qsel < 2; ++qsel) {
        const int qt = qsel ? (nq - 1 - blockIdx.x) : blockIdx.x;
        const int qb0 = qt * 64;

        const int qrow = qb0 + wid * 16 + lr;
        short8 qf[4];
        #pragma unroll
        for (int kk = 0; kk < 4; ++kk)
            qf[kk] = *reinterpret_cast<const short8*>(Qh + (long)qrow * 128 + kk * 32 + lg * 8);

        f32x4 oacc[8] = {};
        float mrow[4], lsum[4];
        #pragma unroll
        for (int r = 0; r < 4; ++r) { mrow[r] = -INFINITY; lsum[r] = 0.f; }

        const int nkt = qt + 1;

        short8 kreg[4], vreg[4];
        {
            const ushort_t* kgp = Kh + t * 32;
            const ushort_t* vgp = Vth + (long)vsr * S + vsc;
            #pragma unroll
            for (int j = 0; j < 4; ++j) kreg[j] = *reinterpret_cast<const short8*>(kgp + j * 8);
            #pragma unroll
            for (int j = 0; j < 4; ++j) vreg[j] = *reinterpret_cast<const short8*>(vgp + j * 8);
        }

        for (int kt = 0; kt < nkt; ++kt) {
            const int kv0 = kt * 64;
            __syncthreads();
            // swizzled LDS writes: slot' = slot ^ (row&7)
            #pragma unroll
            for (int j = 0; j < 4; ++j)
                *reinterpret_cast<short8*>(&Ks[(ksr << 7) + (((((t & 3) << 2) + j) ^ (ksr & 7)) << 3)]) = kreg[j];
            #pragma unroll
            for (int j = 0; j < 4; ++j)
                *reinterpret_cast<short8*>(&Vs[(vsr << 6) + (((((t >> 7) << 2) + j) ^ (vsr & 7)) << 3)]) = vreg[j];
            __syncthreads();
            if (kt + 1 < nkt) {
                const ushort_t* kgp = Kh + (long)(kv0 + 64) * 128 + t * 32;
                const ushort_t* vgp = Vth + (long)vsr * S + kv0 + 64 + vsc;
                #pragma unroll
                for (int j = 0; j < 4; ++j) kreg[j] = *reinterpret_cast<const short8*>(kgp + j * 8);
                #pragma unroll
                for (int j = 0; j < 4; ++j) vreg[j] = *reinterpret_cast<const short8*>(vgp + j * 8);
            }

            f32x4 sacc[4] = {};
            #pragma unroll
            for (int kk = 0; kk < 4; ++kk) {
                #pragma unroll
                for (int n = 0; n < 4; ++n) {
                    short8 kf = *reinterpret_cast<const short8*>(
                        &Ks[((n * 16 + lr) << 7) + ((((kk << 2) + lg) ^ (lr & 7)) << 3)]);
                    sacc[n] = __builtin_amdgcn_mfma_f32_16x16x32_bf16(qf[kk], kf, sacc[n], 0, 0, 0);
                }
            }
            float sv[4][4];
            const int myq = qb0 + wid * 16 + lg * 4;
            #pragma unroll
            for (int n = 0; n < 4; ++n) {
                int kcol = kv0 + n * 16 + lr;
                #pragma unroll
                for (int r = 0; r < 4; ++r) {
                    float xv = sacc[n][r] * scale;
                    sv[n][r] = (kcol > myq + r) ? -1e9f : xv;
                }
            }
            // row maxima
            float mx[4];
            #pragma unroll
            for (int r = 0; r < 4; ++r) {
                float m_ = fmaxf(fmaxf(sv[0][r], sv[1][r]), fmaxf(sv[2][r], sv[3][r]));
                #pragma unroll
                for (int off = 1; off < 16; off <<= 1)
                    m_ = fmaxf(m_, __shfl_xor(m_, off));
                mx[r] = m_;
            }
            // T13 defer-max: skip rescale when max growth <= 8 (wave-uniform)
            int ok = (mx[0] <= mrow[0] + 8.f) && (mx[1] <= mrow[1] + 8.f) &&
                     (mx[2] <= mrow[2] + 8.f) && (mx[3] <= mrow[3] + 8.f);
            if (__all(ok)) {
                #pragma unroll
                for (int r = 0; r < 4; ++r) {
                    float ts = 0.f;
                    #pragma unroll
                    for (int n = 0; n < 4; ++n) {
                        float p = __expf(sv[n][r] - mrow[r]);
                        sv[n][r] = p;
                        ts += p;
                    }
                    #pragma unroll
                    for (int off = 1; off < 16; off <<= 1)
                        ts += __shfl_xor(ts, off);
                    lsum[r] += ts;
                }
            } else {
                float alpha[4];
                #pragma unroll
                for (int r = 0; r < 4; ++r) {
                    float mnew = fmaxf(mrow[r], mx[r]);
                    alpha[r] = __expf(mrow[r] - mnew);
                    float ts = 0.f;
                    #pragma unroll
                    for (int n = 0; n < 4; ++n) {
                        float p = __expf(sv[n][r] - mnew);
                        sv[n][r] = p;
                        ts += p;
                    }
                    #pragma unroll
                    for (int off = 1; off < 16; off <<= 1)
                        ts += __shfl_xor(ts, off);
                    lsum[r] = lsum[r] * alpha[r] + ts;
                    mrow[r] = mnew;
                }
                #pragma unroll
                for (int f = 0; f < 8; ++f)
                    #pragma unroll
                    for (int r = 0; r < 4; ++r)
                        oacc[f][r] *= alpha[r];
            }
            #pragma unroll
            for (int n = 0; n < 4; ++n)
                #pragma unroll
                for (int r = 0; r < 4; ++r)
                    Pl[wid][lg * 4 + r][n * 16 + lr] = f2bf(sv[n][r]);
            __asm volatile("" ::: "memory");
            short8 pf[2];
            #pragma unroll
            for (int ks = 0; ks < 2; ++ks)
                pf[ks] = *reinterpret_cast<const short8*>(&Pl[wid][lr][ks * 32 + lg * 8]);
            #pragma unroll
            for (int ks = 0; ks < 2; ++ks) {
                #pragma unroll
                for (int f = 0; f < 8; ++f) {
                    short8 vf = *reinterpret_cast<const short8*>(
                        &Vs[((f * 16 + lr) << 6) + ((((ks << 2) + lg) ^ (lr & 7)) << 3)]);
                    oacc[f] = __builtin_amdgcn_mfma_f32_16x16x32_bf16(pf[ks], vf, oacc[f], 0, 0, 0);
                }
            }
        }
        float inv[4];
        #pragma unroll
        for (int r = 0; r < 4; ++r) inv[r] = 1.f / lsum[r];
        ushort_t* Oh = O + (long)b * S * 2048 + h * 128;
        #pragma unroll
        for (int f = 0; f < 8; ++f) {
            #pragma unroll
            for (int r = 0; r < 4; ++r) {
                int row = qb0 + wid * 16 + lg * 4 + r;
                int col = f * 16 + lr;
                Oh[(long)row * 2048 + col] = f2bf(oacc[f][r] * inv[r]);
            }
        }
    }
}

extern "C" void kernel_launch(void* const* d_in, const int* in_sizes, int n_in,
                              void* d_out, int out_size, void* d_ws, size_t ws_size,
                              hipStream_t stream) {
    const float* x  = (const float*)d_in[0];
    const float* fc = (const float*)d_in[1];
    const float* fs = (const float*)d_in[2];
    const float* wq = (const float*)d_in[3];
    const float* wk = (const float*)d_in[4];
    const float* wv = (const float*)d_in[5];
    const float* wo = (const float*)d_in[6];
    float* out = (float*)d_out;

    const int B = 2, S = 2048, D = 2048, H = 16;
    const int M = B * S;            // 4096
    const size_t MD = (size_t)M * D;
    const size_t DD = (size_t)D * D;

    char* ws = (char*)d_ws;
    ushort_t* xbf = (ushort_t*)ws;                  // A input; attnb overlay after GEMM
    ushort_t* wqb = (ushort_t*)(ws + MD * 2);       // wq|wk|wv|wo bf16 contiguous
    ushort_t* wob = wqb + 3 * DD;
    ushort_t* qp  = wqb + 4 * DD;                   // Q packed [bh,s,128]
    ushort_t* kp  = qp + MD;                        // K packed
    ushort_t* vtg = kp + MD;                        // V transposed [bh,128,s]
    float2* fcs   = (float2*)(vtg + MD);            // packed (cos,sin) table, 1MB
    ushort_t* attnb = xbf;                          // overlay: x dead after QKV GEMM

    // 1) fused convert + rope table
    const int npair4 = S * 64 / 4;   // 32768
    cvt_all<<<2048, 256, 0, stream>>>(x, wq, wk, wv, wo, fc, fs, xbf, fcs,
                                      (int)(MD / 8), (int)(DD / 8), npair4);

    // 2) fused QKV projection + RoPE + transposed-V epilogue
    dim3 gq(6144 / 256, M / 256);
    gemm256_qkv<<<gq, 512, 131072, stream>>>(xbf, wqb, qp, vtg, fcs, M, 3 * D, D);

    // 3) causal flash attention
    dim3 ga(S / 128, B * H);
    attn_kernel<<<ga, 256, 0, stream>>>(qp, kp, vtg, attnb, S, H);

    // 4) output projection (fp32 out)
    dim3 gg(D / 128, M / 128);
    gemm_nt_f32<<<gg, 256, 0, stream>>>(attnb, wob, out, M, D, D);
}

// Round 10
// 309.101 us; speedup vs baseline: 1.4167x; 1.4167x over previous
//
#include <hip/hip_runtime.h>
#include <hip/hip_bf16.h>
#include <math.h>

typedef __attribute__((ext_vector_type(8))) short short8;
typedef __attribute__((ext_vector_type(4))) short short4v;
typedef __attribute__((ext_vector_type(4))) float f32x4;
typedef unsigned short ushort_t;

__device__ __forceinline__ ushort_t f2bf(float f) {
    union { float f; unsigned u; } v; v.f = f;
    unsigned r = v.u + 0x7FFF + ((v.u >> 16) & 1);
    return (ushort_t)(r >> 16);
}

// ---- fused convert: x|wq|wk|wv|wo -> bf16, plus packed float2 (cos,sin) table ----
__global__ void cvt_all(const float* __restrict__ x,
                        const float* __restrict__ w0, const float* __restrict__ w1,
                        const float* __restrict__ w2, const float* __restrict__ w3,
                        const float* __restrict__ fc, const float* __restrict__ fs,
                        ushort_t* __restrict__ dst, float2* __restrict__ fcs,
                        int md8, int dd8, int npair4) {
    int i = blockIdx.x * blockDim.x + threadIdx.x;
    int stride = gridDim.x * blockDim.x;
    const int total0 = md8 + 4 * dd8;
    const int total = total0 + npair4;
    for (; i < total; i += stride) {
        if (i < total0) {
            const float* src;
            long off;
            if (i < md8) { src = x; off = i; }
            else {
                int j = i - md8;
                int which = j / dd8;
                off = j - (long)which * dd8;
                src = (which == 0) ? w0 : (which == 1) ? w1 : (which == 2) ? w2 : w3;
            }
            const float4* s = reinterpret_cast<const float4*>(src) + off * 2;
            float4 a = s[0], b = s[1];
            short8 o;
            o[0] = (short)f2bf(a.x); o[1] = (short)f2bf(a.y);
            o[2] = (short)f2bf(a.z); o[3] = (short)f2bf(a.w);
            o[4] = (short)f2bf(b.x); o[5] = (short)f2bf(b.y);
            o[6] = (short)f2bf(b.z); o[7] = (short)f2bf(b.w);
            reinterpret_cast<short8*>(dst)[i] = o;
        } else {
            int j = i - total0;
            float4 c4 = reinterpret_cast<const float4*>(fc)[j];
            float4 s4 = reinterpret_cast<const float4*>(fs)[j];
            float2* o = fcs + (long)j * 4;
            o[0] = make_float2(c4.x, s4.x);
            o[1] = make_float2(c4.y, s4.y);
            o[2] = make_float2(c4.z, s4.z);
            o[3] = make_float2(c4.w, s4.w);
        }
    }
}

// ============ 256x256 8-phase GEMM (QKV) + fused RoPE(float2 table) + transposed-V ============
__global__ __launch_bounds__(512, 2) void gemm256_qkv(const ushort_t* __restrict__ A,
                                                      const ushort_t* __restrict__ Bw,
                                                      ushort_t* __restrict__ Cout,
                                                      ushort_t* __restrict__ Vt,
                                                      const float2* __restrict__ fcs,
                                                      int M, int N, int K) {
    extern __shared__ __align__(16) ushort_t lds[];
    ushort_t* As = lds;              // 32768 elems
    ushort_t* Bs = lds + 32768;
    const int t = threadIdx.x;
    const int wid = t >> 6, lane = t & 63;
    const int wr = wid >> 2, wc = wid & 3;
    const int lr = lane & 15, lg = lane >> 4;

    const int ntc = N >> 8;
    const int nwg = (M >> 8) * ntc;
    const int bid = blockIdx.y * gridDim.x + blockIdx.x;
    const int cpx = nwg >> 3;
    const int swz = (bid & 7) * cpx + (bid >> 3);
    const int m0 = (swz / ntc) * 256, n0 = (swz % ntc) * 256;

    f32x4 acc[8][4] = {};

    const int r0 = t >> 3;
    const int c0 = (t & 7) ^ (r0 & 7);
    const ushort_t* gA = A + (long)(m0 + r0) * K + c0 * 8;
    const ushort_t* gB = Bw + (long)(n0 + r0) * K + c0 * 8;

    int aoffE[2];
    aoffE[0] = lr * 64 + (((0 + lg) ^ (lr & 7)) << 3);
    aoffE[1] = lr * 64 + (((4 + lg) ^ (lr & 7)) << 3);

    const int nt = K >> 6;   // 32 (even)

#define STAGE_A(X, h) do { const int p_ = (X) & 1;                                             \
    __builtin_amdgcn_global_load_lds((const __attribute__((address_space(1))) unsigned int*)   \
        (gA + (long)((h) * 128) * K + (X) * 64),                                               \
        (__attribute__((address_space(3))) unsigned int*)(As + (p_ * 2 + (h)) * 8192 + t * 8), \
        16, 0, 0);                                                                             \
    __builtin_amdgcn_global_load_lds((const __attribute__((address_space(1))) unsigned int*)   \
        (gA + (long)((h) * 128 + 64) * K + (X) * 64),                                          \
        (__attribute__((address_space(3))) unsigned int*)(As + (p_ * 2 + (h)) * 8192 + 4096 + t * 8), \
        16, 0, 0); } while (0)

#define STAGE_B(X, h) do { const int p_ = (X) & 1;                                             \
    __builtin_amdgcn_global_load_lds((const __attribute__((address_space(1))) unsigned int*)   \
        (gB + (long)((h) * 128) * K + (X) * 64),                                               \
        (__attribute__((address_space(3))) unsigned int*)(Bs + (p_ * 2 + (h)) * 8192 + t * 8), \
        16, 0, 0);                                                                             \
    __builtin_amdgcn_global_load_lds((const __attribute__((address_space(1))) unsigned int*)   \
        (gB + (long)((h) * 128 + 64) * K + (X) * 64),                                          \
        (__attribute__((address_space(3))) unsigned int*)(Bs + (p_ * 2 + (h)) * 8192 + 4096 + t * 8), \
        16, 0, 0); } while (0)

#define MIDSYNC() do {                                             \
    asm volatile("" ::: "memory");                                 \
    __builtin_amdgcn_s_barrier();                                  \
    asm volatile("s_waitcnt lgkmcnt(0)" ::: "memory");             \
    __builtin_amdgcn_sched_barrier(0); } while (0)

#define ENDBAR() do {                                              \
    asm volatile("" ::: "memory");                                 \
    __builtin_amdgcn_s_barrier(); } while (0)

#define MFMA_Q(AROW, BCOL, AR, BR) do {                            \
    __builtin_amdgcn_s_setprio(1);                                 \
    _Pragma("unroll")                                              \
    for (int ks = 0; ks < 2; ++ks)                                 \
        _Pragma("unroll")                                          \
        for (int m = 0; m < 4; ++m)                                \
            _Pragma("unroll")                                      \
            for (int n = 0; n < 2; ++n)                            \
                acc[(AROW) + m][(BCOL) + n] =                      \
                    __builtin_amdgcn_mfma_f32_16x16x32_bf16((AR)[m][ks], (BR)[n][ks], acc[(AROW) + m][(BCOL) + n], 0, 0, 0); \
    __builtin_amdgcn_s_setprio(0); } while (0)

#define KTILE(U, BUF) do {                                                                     \
    const int Asb = ((BUF) * 2 + wr) * 8192;                                                   \
    const int Bcb = ((BUF) * 2 + (wc >> 1)) * 8192 + (wc & 1) * 4096;                          \
    _Pragma("unroll")                                                                          \
    for (int m = 0; m < 4; ++m)                                                                \
        _Pragma("unroll")                                                                      \
        for (int ks = 0; ks < 2; ++ks)                                                         \
            ar[m][ks] = *reinterpret_cast<const short8*>(&As[Asb + m * 1024 + aoffE[ks]]);     \
    _Pragma("unroll")                                                                          \
    for (int n = 0; n < 2; ++n)                                                                \
        _Pragma("unroll")                                                                      \
        for (int ks = 0; ks < 2; ++ks)                                                         \
            br0[n][ks] = *reinterpret_cast<const short8*>(&Bs[Bcb + n * 1024 + aoffE[ks]]);    \
    if ((U) + 1 < nt) STAGE_A((U) + 1, 1);                                                     \
    MIDSYNC();                                                                                 \
    MFMA_Q(0, 0, ar, br0);                                                                     \
    ENDBAR();                                                                                  \
    _Pragma("unroll")                                                                          \
    for (int n = 0; n < 2; ++n)                                                                \
        _Pragma("unroll")                                                                      \
        for (int ks = 0; ks < 2; ++ks)                                                         \
            br1[n][ks] = *reinterpret_cast<const short8*>(&Bs[Bcb + 2048 + n * 1024 + aoffE[ks]]); \
    MIDSYNC();                                                                                 \
    MFMA_Q(0, 2, ar, br1);                                                                     \
    ENDBAR();                                                                                  \
    _Pragma("unroll")                                                                          \
    for (int m = 0; m < 4; ++m)                                                                \
        _Pragma("unroll")                                                                      \
        for (int ks = 0; ks < 2; ++ks)                                                         \
            ar[m][ks] = *reinterpret_cast<const short8*>(&As[Asb + 4096 + m * 1024 + aoffE[ks]]); \
    if ((U) + 2 < nt) STAGE_B((U) + 2, 0);                                                     \
    MIDSYNC();                                                                                 \
    MFMA_Q(4, 2, ar, br1);                                                                     \
    ENDBAR();                                                                                  \
    if ((U) + 2 < nt) { STAGE_A((U) + 2, 0); STAGE_B((U) + 2, 1); }                            \
    asm volatile("" ::: "memory");                                                             \
    __builtin_amdgcn_s_barrier();                                                              \
    MFMA_Q(4, 0, ar, br0);                                                                     \
    if ((U) < nt - 2) {                                                                        \
        asm volatile("s_waitcnt vmcnt(6)" ::: "memory");                                       \
    } else if ((U) == nt - 2) {                                                                \
        asm volatile("s_waitcnt vmcnt(0)" ::: "memory");                                       \
    }                                                                                          \
    __builtin_amdgcn_s_barrier(); } while (0)

    STAGE_A(0, 0); STAGE_A(0, 1); STAGE_B(0, 0); STAGE_B(0, 1);
    STAGE_A(1, 0); STAGE_B(1, 0); STAGE_B(1, 1);
    asm volatile("s_waitcnt vmcnt(6)" ::: "memory");
    __builtin_amdgcn_s_barrier();

    short8 ar[4][2], br0[2][2], br1[2][2];

    for (int U = 0; U < nt; U += 2) {
        KTILE(U, 0);
        KTILE(U + 1, 1);
    }
#undef KTILE
#undef MFMA_Q
#undef ENDBAR
#undef MIDSYNC
#undef STAGE_A
#undef STAGE_B

    // ---- fused epilogue ----
    const int S = 2048;
    #pragma unroll
    for (int m = 0; m < 8; ++m) {
        #pragma unroll
        for (int n = 0; n < 4; ++n) {
            const int col = n0 + wc * 64 + n * 16 + lr;
            const int which = col >> 11;
            const int h = (col >> 7) & 15;
            const int d = col & 127;
            const int rowb = m0 + wr * 128 + m * 16 + lg * 4;
            const int bb = rowb >> 11;
            const int sb = rowb & 2047;
            if (which == 2) {
                short4v o;
                #pragma unroll
                for (int r = 0; r < 4; ++r) o[r] = (short)f2bf(acc[m][n][r]);
                *reinterpret_cast<short4v*>(Vt + ((long)(bb * 16 + h) * 128 + d) * S + sb) = o;
            } else {
                const int i0 = d >> 1;
                #pragma unroll
                for (int r = 0; r < 4; ++r) {
                    const int s = sb + r;
                    float v = acc[m][n][r];
                    float p = __shfl_xor(v, 1);
                    float2 cs = fcs[(long)s * 64 + i0];
                    float o = (lr & 1) ? (p * cs.y + v * cs.x) : (v * cs.x - p * cs.y);
                    Cout[(long)which * M * 2048 + (((long)(bb * 16 + h)) * 2048 + s) * 128 + d] = f2bf(o);
                }
            }
        }
    }
}

// ---------------- GEMM NT 128x128 (proven 2-phase dbuf) — used for wo ----------------
__global__ __launch_bounds__(256) void gemm_nt_f32(const ushort_t* __restrict__ A,
                                                   const ushort_t* __restrict__ Bw,
                                                   float* __restrict__ Cout,
                                                   int M, int N, int K) {
    __shared__ __align__(16) ushort_t As[2 * 128 * 32];
    __shared__ __align__(16) ushort_t Bs[2 * 128 * 32];
    const int t = threadIdx.x;
    const int wid = t >> 6, lane = t & 63;
    const int wm = wid >> 1, wn = wid & 1;
    const int lr = lane & 15, lg = lane >> 4;

    const int ntc = N >> 7;
    const int nwg = (M >> 7) * ntc;
    const int bid = blockIdx.y * gridDim.x + blockIdx.x;
    const int cpx = nwg >> 3;
    const int swz = (bid & 7) * cpx + (bid >> 3);
    const int m0 = (swz / ntc) * 128, n0 = (swz % ntc) * 128;

    f32x4 acc[4][4] = {};

    const int sh0 = wid * 1024 + lane * 8;
    const int sh1 = sh0 + 512;
    const int r0 = sh0 >> 5, c0 = sh0 & 31;
    const int r1 = sh1 >> 5, c1 = sh1 & 31;

    const ushort_t* gA0 = A + (long)(m0 + r0) * K + c0;
    const ushort_t* gA1 = A + (long)(m0 + r1) * K + c1;
    const ushort_t* gB0 = Bw + (long)(n0 + r0) * K + c0;
    const ushort_t* gB1 = Bw + (long)(n0 + r1) * K + c1;

    auto stage = [&](int k0, int nb) {
        ushort_t* as = As + nb * 4096;
        ushort_t* bs = Bs + nb * 4096;
        __builtin_amdgcn_global_load_lds((const __attribute__((address_space(1))) unsigned int*)(gA0 + k0),
                                         (__attribute__((address_space(3))) unsigned int*)(as + sh0), 16, 0, 0);
        __builtin_amdgcn_global_load_lds((const __attribute__((address_space(1))) unsigned int*)(gA1 + k0),
                                         (__attribute__((address_space(3))) unsigned int*)(as + sh1), 16, 0, 0);
        __builtin_amdgcn_global_load_lds((const __attribute__((address_space(1))) unsigned int*)(gB0 + k0),
                                         (__attribute__((address_space(3))) unsigned int*)(bs + sh0), 16, 0, 0);
        __builtin_amdgcn_global_load_lds((const __attribute__((address_space(1))) unsigned int*)(gB1 + k0),
                                         (__attribute__((address_space(3))) unsigned int*)(bs + sh1), 16, 0, 0);
    };

    const int nt = K >> 5;
    stage(0, 0);
    __syncthreads();
    int cur = 0;

    for (int ti = 0; ti < nt; ++ti) {
        if (ti + 1 < nt) stage((ti + 1) << 5, cur ^ 1);
        const ushort_t* as = As + cur * 4096;
        const ushort_t* bs = Bs + cur * 4096;
        short8 af[4], bfr[4];
        #pragma unroll
        for (int m = 0; m < 4; ++m)
            af[m] = *reinterpret_cast<const short8*>(&as[(wm * 64 + m * 16 + lr) * 32 + lg * 8]);
        #pragma unroll
        for (int n = 0; n < 4; ++n)
            bfr[n] = *reinterpret_cast<const short8*>(&bs[(wn * 64 + n * 16 + lr) * 32 + lg * 8]);
        #pragma unroll
        for (int m = 0; m < 4; ++m)
            #pragma unroll
            for (int n = 0; n < 4; ++n)
                acc[m][n] = __builtin_amdgcn_mfma_f32_16x16x32_bf16(af[m], bfr[n], acc[m][n], 0, 0, 0);
        __syncthreads();
        cur ^= 1;
    }

    #pragma unroll
    for (int m = 0; m < 4; ++m) {
        #pragma unroll
        for (int n = 0; n < 4; ++n) {
            const int col = n0 + wn * 64 + n * 16 + lr;
            #pragma unroll
            for (int r = 0; r < 4; ++r) {
                const int row = m0 + wm * 64 + m * 16 + lg * 4 + r;
                Cout[(long)row * N + col] = acc[m][n][r];
            }
        }
    }
}

// ---------------- causal flash attention (round-8 structure + K/V swizzle ONLY) ----------------
__global__ __launch_bounds__(256, 3) void attn_kernel(const ushort_t* __restrict__ Qp,
                                                      const ushort_t* __restrict__ Kp,
                                                      const ushort_t* __restrict__ Vtg,
                                                      ushort_t* __restrict__ O,
                                                      int S, int H) {
    __shared__ __align__(16) ushort_t Ks[64 * 128];   // linear, XOR-swizzled 16B slots
    __shared__ __align__(16) ushort_t Vs[128 * 64];   // linear, XOR-swizzled 16B slots
    __shared__ __align__(16) ushort_t Pl[4][16][72];
    const int t = threadIdx.x, wid = t >> 6, lane = t & 63;
    const int lr = lane & 15, lg = lane >> 4;
    const int bh = blockIdx.y;
    const int b = bh / H, h = bh % H;
    const ushort_t* Qh = Qp + (long)bh * S * 128;
    const ushort_t* Kh = Kp + (long)bh * S * 128;
    const ushort_t* Vth = Vtg + (long)bh * 128 * S;
    const int nq = S / 64;
    const float scale = 0.08838834764831845f;

    const int ksr = t >> 2;          // K stage row 0..63
    const int vsr = t & 127;         // V stage row (d)
    const int vsc = (t >> 7) * 32;   // V stage col base

    for (int qsel = 0; qsel < 2; ++qsel) {
        const int qt = qsel ? (nq - 1 - blockIdx.x) : blockIdx.x;
        const int qb0 = qt * 64;

        const int qrow = qb0 + wid * 16 + lr;
        short8 qf[4];
        #pragma unroll
        for (int kk = 0; kk < 4; ++kk)
            qf[kk] = *reinterpret_cast<const short8*>(Qh + (long)qrow * 128 + kk * 32 + lg * 8);

        f32x4 oacc[8] = {};
        float mrow[4], lsum[4];
        #pragma unroll
        for (int r = 0; r < 4; ++r) { mrow[r] = -INFINITY; lsum[r] = 0.f; }

        const int nkt = qt + 1;

        short8 kreg[4], vreg[4];
        {
            const ushort_t* kgp = Kh + t * 32;
            const ushort_t* vgp = Vth + (long)vsr * S + vsc;
            #pragma unroll
            for (int j = 0; j < 4; ++j) kreg[j] = *reinterpret_cast<const short8*>(kgp + j * 8);
            #pragma unroll
            for (int j = 0; j < 4; ++j) vreg[j] = *reinterpret_cast<const short8*>(vgp + j * 8);
        }

        for (int kt = 0; kt < nkt; ++kt) {
            const int kv0 = kt * 64;
            __syncthreads();
            // swizzled LDS writes: 16B-slot' = slot ^ (row&7)
            #pragma unroll
            for (int j = 0; j < 4; ++j)
                *reinterpret_cast<short8*>(&Ks[(ksr << 7) + (((((t & 3) << 2) + j) ^ (ksr & 7)) << 3)]) = kreg[j];
            #pragma unroll
            for (int j = 0; j < 4; ++j)
                *reinterpret_cast<short8*>(&Vs[(vsr << 6) + (((((t >> 7) << 2) + j) ^ (vsr & 7)) << 3)]) = vreg[j];
            __syncthreads();
            if (kt + 1 < nkt) {
                const ushort_t* kgp = Kh + (long)(kv0 + 64) * 128 + t * 32;
                const ushort_t* vgp = Vth + (long)vsr * S + kv0 + 64 + vsc;
                #pragma unroll
                for (int j = 0; j < 4; ++j) kreg[j] = *reinterpret_cast<const short8*>(kgp + j * 8);
                #pragma unroll
                for (int j = 0; j < 4; ++j) vreg[j] = *reinterpret_cast<const short8*>(vgp + j * 8);
            }

            f32x4 sacc[4] = {};
            #pragma unroll
            for (int kk = 0; kk < 4; ++kk) {
                #pragma unroll
                for (int n = 0; n < 4; ++n) {
                    short8 kf = *reinterpret_cast<const short8*>(
                        &Ks[((n * 16 + lr) << 7) + ((((kk << 2) + lg) ^ (lr & 7)) << 3)]);
                    sacc[n] = __builtin_amdgcn_mfma_f32_16x16x32_bf16(qf[kk], kf, sacc[n], 0, 0, 0);
                }
            }
            float sv[4][4];
            const int myq = qb0 + wid * 16 + lg * 4;
            #pragma unroll
            for (int n = 0; n < 4; ++n) {
                int kcol = kv0 + n * 16 + lr;
                #pragma unroll
                for (int r = 0; r < 4; ++r) {
                    float xv = sacc[n][r] * scale;
                    sv[n][r] = (kcol > myq + r) ? -1e9f : xv;
                }
            }
            float alpha[4];
            #pragma unroll
            for (int r = 0; r < 4; ++r) {
                float mx = fmaxf(fmaxf(sv[0][r], sv[1][r]), fmaxf(sv[2][r], sv[3][r]));
                #pragma unroll
                for (int off = 1; off < 16; off <<= 1)
                    mx = fmaxf(mx, __shfl_xor(mx, off));
                float mnew = fmaxf(mrow[r], mx);
                alpha[r] = __expf(mrow[r] - mnew);
                float ts = 0.f;
                #pragma unroll
                for (int n = 0; n < 4; ++n) {
                    float p = __expf(sv[n][r] - mnew);
                    sv[n][r] = p;
                    ts += p;
                }
                #pragma unroll
                for (int off = 1; off < 16; off <<= 1)
                    ts += __shfl_xor(ts, off);
                lsum[r] = lsum[r] * alpha[r] + ts;
                mrow[r] = mnew;
            }
            #pragma unroll
            for (int f = 0; f < 8; ++f)
                #pragma unroll
                for (int r = 0; r < 4; ++r)
                    oacc[f][r] *= alpha[r];
            #pragma unroll
            for (int n = 0; n < 4; ++n)
                #pragma unroll
                for (int r = 0; r < 4; ++r)
                    Pl[wid][lg * 4 + r][n * 16 + lr] = f2bf(sv[n][r]);
            __asm volatile("" ::: "memory");
            short8 pf[2];
            #pragma unroll
            for (int ks = 0; ks < 2; ++ks)
                pf[ks] = *reinterpret_cast<const short8*>(&Pl[wid][lr][ks * 32 + lg * 8]);
            #pragma unroll
            for (int ks = 0; ks < 2; ++ks) {
                #pragma unroll
                for (int f = 0; f < 8; ++f) {
                    short8 vf = *reinterpret_cast<const short8*>(
                        &Vs[((f * 16 + lr) << 6) + ((((ks << 2) + lg) ^ (lr & 7)) << 3)]);
                    oacc[f] = __builtin_amdgcn_mfma_f32_16x16x32_bf16(pf[ks], vf, oacc[f], 0, 0, 0);
                }
            }
        }
        float inv[4];
        #pragma unroll
        for (int r = 0; r < 4; ++r) inv[r] = 1.f / lsum[r];
        ushort_t* Oh = O + (long)b * S * 2048 + h * 128;
        #pragma unroll
        for (int f = 0; f < 8; ++f) {
            #pragma unroll
            for (int r = 0; r < 4; ++r) {
                int row = qb0 + wid * 16 + lg * 4 + r;
                int col = f * 16 + lr;
                Oh[(long)row * 2048 + col] = f2bf(oacc[f][r] * inv[r]);
            }
        }
    }
}

extern "C" void kernel_launch(void* const* d_in, const int* in_sizes, int n_in,
                              void* d_out, int out_size, void* d_ws, size_t ws_size,
                              hipStream_t stream) {
    const float* x  = (const float*)d_in[0];
    const float* fc = (const float*)d_in[1];
    const float* fs = (const float*)d_in[2];
    const float* wq = (const float*)d_in[3];
    const float* wk = (const float*)d_in[4];
    const float* wv = (const float*)d_in[5];
    const float* wo = (const float*)d_in[6];
    float* out = (float*)d_out;

    const int B = 2, S = 2048, D = 2048, H = 16;
    const int M = B * S;            // 4096
    const size_t MD = (size_t)M * D;
    const size_t DD = (size_t)D * D;

    char* ws = (char*)d_ws;
    ushort_t* xbf = (ushort_t*)ws;                  // A input; attnb overlay after GEMM
    ushort_t* wqb = (ushort_t*)(ws + MD * 2);       // wq|wk|wv|wo bf16 contiguous
    ushort_t* wob = wqb + 3 * DD;
    ushort_t* qp  = wqb + 4 * DD;                   // Q packed [bh,s,128]
    ushort_t* kp  = qp + MD;                        // K packed
    ushort_t* vtg = kp + MD;                        // V transposed [bh,128,s]
    float2* fcs   = (float2*)(vtg + MD);            // packed (cos,sin) table, 1MB
    ushort_t* attnb = xbf;                          // overlay: x dead after QKV GEMM

    // 1) fused convert + rope table
    const int npair4 = S * 64 / 4;   // 32768
    cvt_all<<<2048, 256, 0, stream>>>(x, wq, wk, wv, wo, fc, fs, xbf, fcs,
                                      (int)(MD / 8), (int)(DD / 8), npair4);

    // 2) fused QKV projection + RoPE + transposed-V epilogue
    dim3 gq(6144 / 256, M / 256);
    gemm256_qkv<<<gq, 512, 131072, stream>>>(xbf, wqb, qp, vtg, fcs, M, 3 * D, D);

    // 3) causal flash attention
    dim3 ga(S / 128, B * H);
    attn_kernel<<<ga, 256, 0, stream>>>(qp, kp, vtg, attnb, S, H);

    // 4) output projection (fp32 out)
    dim3 gg(D / 128, M / 128);
    gemm_nt_f32<<<gg, 256, 0, stream>>>(attnb, wob, out, M, D, D);
}